// Round 6
// baseline (1347.859 us; speedup 1.0000x reference)
//
#include <hip/hip_runtime.h>
#include <hip/hip_bf16.h>
#include <math.h>

// Problem constants: B=2,S=2048 -> T=4096 tokens, H=2048, E=8, I=768, top-2
#define TT 4096
#define HH 2048
#define EE 8
#define II 768
#define TWOI 1536

typedef __attribute__((ext_vector_type(8))) short bf16v8;   // 8 bf16 = 4 VGPR
typedef __attribute__((ext_vector_type(4))) float f32x4;

// round-to-nearest-even fp32 -> bf16 (bits)
static __device__ __forceinline__ unsigned short f2bf(float f) {
    unsigned int u = __float_as_uint(f);
    unsigned int r = (u + 0x7fffu + ((u >> 16) & 1u)) >> 16;
    return (unsigned short)r;
}
static __device__ __forceinline__ float bf2f(unsigned short b) {
    return __uint_as_float(((unsigned int)b) << 16);
}
// 8 floats -> hi uint4 (8 bf16) and lo uint4 (residual 8 bf16)
static __device__ __forceinline__ void cvt8(const float4 v0, const float4 v1,
                                            uint4& hi, uint4& lo) {
    float f[8] = {v0.x, v0.y, v0.z, v0.w, v1.x, v1.y, v1.z, v1.w};
    unsigned short h[8], l[8];
#pragma unroll
    for (int i = 0; i < 8; ++i) {
        h[i] = f2bf(f[i]);
        l[i] = f2bf(f[i] - bf2f(h[i]));
    }
    hi = make_uint4((unsigned)h[0] | ((unsigned)h[1] << 16),
                    (unsigned)h[2] | ((unsigned)h[3] << 16),
                    (unsigned)h[4] | ((unsigned)h[5] << 16),
                    (unsigned)h[6] | ((unsigned)h[7] << 16));
    lo = make_uint4((unsigned)l[0] | ((unsigned)l[1] << 16),
                    (unsigned)l[2] | ((unsigned)l[3] << 16),
                    (unsigned)l[4] | ((unsigned)l[5] << 16),
                    (unsigned)l[6] | ((unsigned)l[7] << 16));
}

// ---------------------------------------------------------------------------
// Weight pre-pass: split fp32 -> (hi, lo) bf16 arrays. Memory-bound.
// ---------------------------------------------------------------------------
__global__ __launch_bounds__(256) void cvt_split(
    const float* __restrict__ src, unsigned short* __restrict__ hi,
    unsigned short* __restrict__ lo, int n8)
{
    int i = blockIdx.x * 256 + threadIdx.x;
    const int stride = gridDim.x * 256;
    for (; i < n8; i += stride) {
        const float4 a = ((const float4*)src)[2 * i];
        const float4 b = ((const float4*)src)[2 * i + 1];
        uint4 h, l;
        cvt8(a, b, h, l);
        ((uint4*)hi)[i] = h;
        ((uint4*)lo)[i] = l;
    }
}

// ---------------------------------------------------------------------------
// Router: one wave per token. Optionally fuses the x hi/lo split (do_split).
// ---------------------------------------------------------------------------
__global__ __launch_bounds__(256) void router_kernel(
    const float* __restrict__ x, const float* __restrict__ gw,
    float* __restrict__ logits_out, int* __restrict__ counts,
    int* __restrict__ bucket_tok, float* __restrict__ bucket_w,
    unsigned short* __restrict__ xhi, unsigned short* __restrict__ xlo,
    int do_split)
{
    const int wave = threadIdx.x >> 6;
    const int lane = threadIdx.x & 63;
    const int t = blockIdx.x * 4 + wave;

    float acc[EE];
#pragma unroll
    for (int e = 0; e < EE; ++e) acc[e] = 0.f;

    const float4* xr = (const float4*)(x + (size_t)t * HH);
    for (int i = lane; i < HH / 4; i += 64) {
        const float4 v = xr[i];
        const float* g = gw + (size_t)(i * 4) * EE;
#pragma unroll
        for (int e = 0; e < EE; ++e)
            acc[e] += v.x * g[e] + v.y * g[e + EE]
                    + v.z * g[e + 2 * EE] + v.w * g[e + 3 * EE];
        if (do_split) {
            const unsigned short h0 = f2bf(v.x), h1 = f2bf(v.y),
                                 h2 = f2bf(v.z), h3 = f2bf(v.w);
            const unsigned short l0 = f2bf(v.x - bf2f(h0)),
                                 l1 = f2bf(v.y - bf2f(h1)),
                                 l2 = f2bf(v.z - bf2f(h2)),
                                 l3 = f2bf(v.w - bf2f(h3));
            *(uint2*)(xhi + (size_t)t * HH + i * 4) =
                make_uint2((unsigned)h0 | ((unsigned)h1 << 16),
                           (unsigned)h2 | ((unsigned)h3 << 16));
            *(uint2*)(xlo + (size_t)t * HH + i * 4) =
                make_uint2((unsigned)l0 | ((unsigned)l1 << 16),
                           (unsigned)l2 | ((unsigned)l3 << 16));
        }
    }
#pragma unroll
    for (int e = 0; e < EE; ++e) {
#pragma unroll
        for (int off = 32; off > 0; off >>= 1)
            acc[e] += __shfl_xor(acc[e], off, 64);
    }

    if (lane == 0) {
        float mx = acc[0];
#pragma unroll
        for (int e = 1; e < EE; ++e) mx = fmaxf(mx, acc[e]);
        float p[EE]; float s = 0.f;
#pragma unroll
        for (int e = 0; e < EE; ++e) { p[e] = expf(acc[e] - mx); s += p[e]; }
        const float inv = 1.f / s;
#pragma unroll
        for (int e = 0; e < EE; ++e) {
            p[e] *= inv;
            logits_out[(size_t)t * EE + e] = acc[e];
        }
        int i0 = 0;
#pragma unroll
        for (int e = 1; e < EE; ++e) if (p[e] > p[i0]) i0 = e;
        int i1 = (i0 == 0) ? 1 : 0;
#pragma unroll
        for (int e = 0; e < EE; ++e) if (e != i0 && p[e] > p[i1]) i1 = e;
        const float denom = 1.f / (p[i0] + p[i1]);
        const float w0 = p[i0] * denom, w1 = p[i1] * denom;
        int pos0 = atomicAdd(&counts[i0], 1);
        bucket_tok[i0 * TT + pos0] = t; bucket_w[i0 * TT + pos0] = w0;
        int pos1 = atomicAdd(&counts[i1], 1);
        bucket_tok[i1 * TT + pos1] = t; bucket_w[i1 * TT + pos1] = w1;
    }
}

__global__ __launch_bounds__(256) void finalize_router(
    const float* __restrict__ logits, const int* __restrict__ counts,
    int* __restrict__ offsets, float* __restrict__ aux_out)
{
    __shared__ float sums[EE];
    if (threadIdx.x < EE) sums[threadIdx.x] = 0.f;
    __syncthreads();
    float loc[EE];
#pragma unroll
    for (int e = 0; e < EE; ++e) loc[e] = 0.f;
    for (int t = threadIdx.x; t < TT; t += 256) {
        const float* lr = logits + (size_t)t * EE;
        float l[EE]; float mx = -1e30f;
#pragma unroll
        for (int e = 0; e < EE; ++e) { l[e] = lr[e]; mx = fmaxf(mx, l[e]); }
        float s = 0.f, p[EE];
#pragma unroll
        for (int e = 0; e < EE; ++e) { p[e] = expf(l[e] - mx); s += p[e]; }
        const float inv = 1.f / s;
#pragma unroll
        for (int e = 0; e < EE; ++e) loc[e] += p[e] * inv;
    }
#pragma unroll
    for (int e = 0; e < EE; ++e) atomicAdd(&sums[e], loc[e]);
    __syncthreads();
    if (threadIdx.x == 0) {
        int o = 0; float aux = 0.f;
        for (int e = 0; e < EE; ++e) {
            offsets[e] = o; o += counts[e];
            aux += (sums[e] / (float)TT) * ((float)counts[e] / (float)TT);
        }
        aux_out[0] = aux * (float)EE * 0.001f;
    }
}

// ===========================================================================
// v2 GEMMs: pre-split bf16 operands, BK=64 (128B LDS rows, 8x16B units),
// XOR-swizzle unit ^= row&7 (conflict-free read AND write, G4 formula).
// LDS 4 x 16 KB = 64 KB. 4 waves 2x2, 96 MFMA / K-step / wave.
// ===========================================================================
#define AHI 0
#define ALO 16384
#define BHI 32768
#define BLO 49152

// Stage 1: gate_up + SiLU -> inter (hi/lo bf16).
__global__ __launch_bounds__(256, 2) void moe_gateup_v2(
    const unsigned short* __restrict__ xhi, const unsigned short* __restrict__ xlo,
    const unsigned short* __restrict__ guhi, const unsigned short* __restrict__ gulo,
    const int* __restrict__ counts, const int* __restrict__ offsets,
    const int* __restrict__ bucket_tok,
    unsigned short* __restrict__ ihi, unsigned short* __restrict__ ilo)
{
    const int bid = blockIdx.x;
    const int e = bid & 7;                    // expert -> XCD
    const int rem = bid >> 3;                 // 0..383
    const int mb = rem / 12, nb = rem % 12;

    const int cnt = counts[e];
    const int m0 = mb * 128;
    if (m0 >= cnt) return;
    const int n0 = nb * 64;                   // pair-col base
    const int base = offsets[e];

    __shared__ unsigned char smem[65536];

    const int tid = threadIdx.x;
    const int lane = tid & 63;
    const int wid = tid >> 6;
    const int wm = wid >> 1, wn = wid & 1;

    // staging: thread -> (row, k-seg); 4 uint4 per component
    const int srow = tid >> 1;                // 0..127
    const int sseg = tid & 1;                 // k offset 32*sseg (bf16 elems)
    const int arow = m0 + srow;
    const int atok = (arow < cnt) ? bucket_tok[e * TT + arow] : 0;
    const size_t aoffg = (size_t)atok * HH + sseg * 32;
    const int bblk = srow >> 5, bc = srow & 31;
    const int bj = ((bblk & 1) ? II : 0) + n0 + ((bblk >> 1) << 5) + bc;
    const size_t boffg = ((size_t)e * TWOI + bj) * HH + sseg * 32;

    // swizzled LDS write offsets: unit u = sseg*4 + j, phys = u ^ (srow&7)
    int wu[4];
#pragma unroll
    for (int j = 0; j < 4; ++j)
        wu[j] = srow * 128 + ((((sseg << 2) | j) ^ (srow & 7)) << 4);

    // fragment read offsets per (ks, frag)
    int aoff[2][4], boff[2][4];
#pragma unroll
    for (int ks = 0; ks < 2; ++ks)
#pragma unroll
        for (int i = 0; i < 4; ++i) {
            const int ra = wm * 64 + i * 16 + (lane & 15);
            aoff[ks][i] = ra * 128 + ((((ks << 2) | (lane >> 4)) ^ (ra & 7)) << 4);
            const int rb = wn * 64 + i * 16 + (lane & 15);
            boff[ks][i] = rb * 128 + ((((ks << 2) | (lane >> 4)) ^ (rb & 7)) << 4);
        }

    f32x4 acc[4][4];
#pragma unroll
    for (int i = 0; i < 4; ++i)
#pragma unroll
        for (int j = 0; j < 4; ++j) acc[i][j] = f32x4{0.f, 0.f, 0.f, 0.f};

    uint4 pAh[4], pAl[4], pBh[4], pBl[4];
#pragma unroll
    for (int j = 0; j < 4; ++j) {
        pAh[j] = *(const uint4*)(xhi + aoffg + j * 8);
        pAl[j] = *(const uint4*)(xlo + aoffg + j * 8);
        pBh[j] = *(const uint4*)(guhi + boffg + j * 8);
        pBl[j] = *(const uint4*)(gulo + boffg + j * 8);
    }

    const int NS = HH / 64;                   // 32 K-steps
    for (int s = 0; s < NS; ++s) {
        __syncthreads();
#pragma unroll
        for (int j = 0; j < 4; ++j) {
            *(uint4*)(smem + AHI + wu[j]) = pAh[j];
            *(uint4*)(smem + ALO + wu[j]) = pAl[j];
            *(uint4*)(smem + BHI + wu[j]) = pBh[j];
            *(uint4*)(smem + BLO + wu[j]) = pBl[j];
        }
        __syncthreads();
        if (s + 1 < NS) {
            const int k0 = (s + 1) * 64;
#pragma unroll
            for (int j = 0; j < 4; ++j) {
                pAh[j] = *(const uint4*)(xhi + aoffg + k0 + j * 8);
                pAl[j] = *(const uint4*)(xlo + aoffg + k0 + j * 8);
                pBh[j] = *(const uint4*)(guhi + boffg + k0 + j * 8);
                pBl[j] = *(const uint4*)(gulo + boffg + k0 + j * 8);
            }
        }
#pragma unroll
        for (int ks = 0; ks < 2; ++ks) {
            bf16v8 ah[4], al[4], bh[4], bl[4];
#pragma unroll
            for (int i = 0; i < 4; ++i) {
                ah[i] = *(const bf16v8*)(smem + AHI + aoff[ks][i]);
                al[i] = *(const bf16v8*)(smem + ALO + aoff[ks][i]);
                bh[i] = *(const bf16v8*)(smem + BHI + boff[ks][i]);
                bl[i] = *(const bf16v8*)(smem + BLO + boff[ks][i]);
            }
#pragma unroll
            for (int i = 0; i < 4; ++i)
#pragma unroll
                for (int j = 0; j < 4; ++j) {
                    acc[i][j] = __builtin_amdgcn_mfma_f32_16x16x32_bf16(ah[i], bh[j], acc[i][j], 0, 0, 0);
                    acc[i][j] = __builtin_amdgcn_mfma_f32_16x16x32_bf16(ah[i], bl[j], acc[i][j], 0, 0, 0);
                    acc[i][j] = __builtin_amdgcn_mfma_f32_16x16x32_bf16(al[i], bh[j], acc[i][j], 0, 0, 0);
                }
        }
    }

    // epilogue: SiLU(gate)*up -> hi/lo bf16 inter
#pragma unroll
    for (int mi = 0; mi < 4; ++mi)
#pragma unroll
        for (int np = 0; np < 2; ++np) {
            const f32x4 g = acc[mi][np], u = acc[mi][np + 2];
            const int colp = n0 + wn * 32 + np * 16 + (lane & 15);
#pragma unroll
            for (int j = 0; j < 4; ++j) {
                const int r = m0 + wm * 64 + mi * 16 + ((lane >> 4) << 2) + j;
                if (r < cnt) {
                    const float gg = g[j];
                    const float val = gg / (1.f + expf(-gg)) * u[j];
                    const unsigned short h = f2bf(val);
                    const unsigned short l = f2bf(val - bf2f(h));
                    ihi[(size_t)(base + r) * II + colp] = h;
                    ilo[(size_t)(base + r) * II + colp] = l;
                }
            }
        }
}

// Stage 2: down proj, weighted atomic scatter.
__global__ __launch_bounds__(256, 2) void moe_down_v2(
    const unsigned short* __restrict__ ihi, const unsigned short* __restrict__ ilo,
    const unsigned short* __restrict__ wdhi, const unsigned short* __restrict__ wdlo,
    const int* __restrict__ counts, const int* __restrict__ offsets,
    const int* __restrict__ bucket_tok, const float* __restrict__ bucket_w,
    float* __restrict__ out)
{
    const int bid = blockIdx.x;
    const int e = bid & 7;
    const int rem = bid >> 3;                 // 0..511
    const int mb = rem >> 4, nb = rem & 15;

    const int cnt = counts[e];
    const int m0 = mb * 128;
    if (m0 >= cnt) return;
    const int n0 = nb * 128;
    const int base = offsets[e];

    __shared__ unsigned char smem[65536];

    const int tid = threadIdx.x;
    const int lane = tid & 63;
    const int wid = tid >> 6;
    const int wm = wid >> 1, wn = wid & 1;

    const int srow = tid >> 1;
    const int sseg = tid & 1;
    const int arow = m0 + srow;
    const int asafe = (arow < cnt) ? arow : 0;
    const size_t aoffg = (size_t)(base + asafe) * II + sseg * 32;
    const size_t boffg = ((size_t)e * HH + n0 + srow) * II + sseg * 32;

    int wu[4];
#pragma unroll
    for (int j = 0; j < 4; ++j)
        wu[j] = srow * 128 + ((((sseg << 2) | j) ^ (srow & 7)) << 4);

    int aoff[2][4], boff[2][4];
#pragma unroll
    for (int ks = 0; ks < 2; ++ks)
#pragma unroll
        for (int i = 0; i < 4; ++i) {
            const int ra = wm * 64 + i * 16 + (lane & 15);
            aoff[ks][i] = ra * 128 + ((((ks << 2) | (lane >> 4)) ^ (ra & 7)) << 4);
            const int rb = wn * 64 + i * 16 + (lane & 15);
            boff[ks][i] = rb * 128 + ((((ks << 2) | (lane >> 4)) ^ (rb & 7)) << 4);
        }

    f32x4 acc[4][4];
#pragma unroll
    for (int i = 0; i < 4; ++i)
#pragma unroll
        for (int j = 0; j < 4; ++j) acc[i][j] = f32x4{0.f, 0.f, 0.f, 0.f};

    uint4 pAh[4], pAl[4], pBh[4], pBl[4];
#pragma unroll
    for (int j = 0; j < 4; ++j) {
        pAh[j] = *(const uint4*)(ihi + aoffg + j * 8);
        pAl[j] = *(const uint4*)(ilo + aoffg + j * 8);
        pBh[j] = *(const uint4*)(wdhi + boffg + j * 8);
        pBl[j] = *(const uint4*)(wdlo + boffg + j * 8);
    }

    const int NS = II / 64;                   // 12 K-steps
    for (int s = 0; s < NS; ++s) {
        __syncthreads();
#pragma unroll
        for (int j = 0; j < 4; ++j) {
            *(uint4*)(smem + AHI + wu[j]) = pAh[j];
            *(uint4*)(smem + ALO + wu[j]) = pAl[j];
            *(uint4*)(smem + BHI + wu[j]) = pBh[j];
            *(uint4*)(smem + BLO + wu[j]) = pBl[j];
        }
        __syncthreads();
        if (s + 1 < NS) {
            const int k0 = (s + 1) * 64;
#pragma unroll
            for (int j = 0; j < 4; ++j) {
                pAh[j] = *(const uint4*)(ihi + aoffg + k0 + j * 8);
                pAl[j] = *(const uint4*)(ilo + aoffg + k0 + j * 8);
                pBh[j] = *(const uint4*)(wdhi + boffg + k0 + j * 8);
                pBl[j] = *(const uint4*)(wdlo + boffg + k0 + j * 8);
            }
        }
#pragma unroll
        for (int ks = 0; ks < 2; ++ks) {
            bf16v8 ah[4], al[4], bh[4], bl[4];
#pragma unroll
            for (int i = 0; i < 4; ++i) {
                ah[i] = *(const bf16v8*)(smem + AHI + aoff[ks][i]);
                al[i] = *(const bf16v8*)(smem + ALO + aoff[ks][i]);
                bh[i] = *(const bf16v8*)(smem + BHI + boff[ks][i]);
                bl[i] = *(const bf16v8*)(smem + BLO + boff[ks][i]);
            }
#pragma unroll
            for (int i = 0; i < 4; ++i)
#pragma unroll
                for (int j = 0; j < 4; ++j) {
                    acc[i][j] = __builtin_amdgcn_mfma_f32_16x16x32_bf16(ah[i], bh[j], acc[i][j], 0, 0, 0);
                    acc[i][j] = __builtin_amdgcn_mfma_f32_16x16x32_bf16(ah[i], bl[j], acc[i][j], 0, 0, 0);
                    acc[i][j] = __builtin_amdgcn_mfma_f32_16x16x32_bf16(al[i], bh[j], acc[i][j], 0, 0, 0);
                }
        }
    }

#pragma unroll
    for (int mi = 0; mi < 4; ++mi) {
        int rtok[4]; float rw[4]; int rok[4];
#pragma unroll
        for (int j = 0; j < 4; ++j) {
            const int r = m0 + wm * 64 + mi * 16 + ((lane >> 4) << 2) + j;
            rok[j] = (r < cnt);
            rtok[j] = rok[j] ? bucket_tok[e * TT + r] : 0;
            rw[j] = rok[j] ? bucket_w[e * TT + r] : 0.f;
        }
#pragma unroll
        for (int ni = 0; ni < 4; ++ni) {
            const int col = n0 + wn * 64 + ni * 16 + (lane & 15);
#pragma unroll
            for (int j = 0; j < 4; ++j)
                if (rok[j])
                    atomicAdd(out + (size_t)rtok[j] * HH + col, rw[j] * acc[mi][ni][j]);
        }
    }
}

// ===========================================================================
// R4 fallback GEMMs (in-loop conversion, BK=32) — used if ws_size is small.
// ===========================================================================
#define AHI1 0
#define ALO1 8192
#define BHI1 16384
#define BLO1 24576

__global__ __launch_bounds__(256, 2) void moe_gateup_r4(
    const float* __restrict__ x, const float* __restrict__ Wgu,
    const int* __restrict__ counts, const int* __restrict__ offsets,
    const int* __restrict__ bucket_tok, float* __restrict__ inter)
{
    const int bid = blockIdx.x;
    const int e = bid & 7;
    const int rem = bid >> 3;
    const int mb = rem / 12, nb = rem % 12;
    const int cnt = counts[e];
    const int m0 = mb * 128;
    if (m0 >= cnt) return;
    const int n0 = nb * 64;
    const int base = offsets[e];
    __shared__ unsigned char smem[32768];
    const int tid = threadIdx.x;
    const int lane = tid & 63;
    const int wid = tid >> 6;
    const int wm = wid >> 1, wn = wid & 1;
    const int srow = tid >> 1;
    const int sseg = tid & 1;
    const int arow = m0 + srow;
    const int atok = (arow < cnt) ? bucket_tok[e * TT + arow] : 0;
    const float* ag = x + (size_t)atok * HH + sseg * 16;
    const int bblk = srow >> 5, bc = srow & 31;
    const int bj = ((bblk & 1) ? II : 0) + n0 + ((bblk >> 1) << 5) + bc;
    const float* bg = Wgu + ((size_t)e * TWOI + bj) * HH + sseg * 16;
    const int au0 = srow * 64 + (((sseg << 1) | 0) ^ (srow & 3)) * 16;
    const int au1 = srow * 64 + (((sseg << 1) | 1) ^ (srow & 3)) * 16;
    int aoff[4], boff[4];
#pragma unroll
    for (int i = 0; i < 4; ++i) {
        int ra = wm * 64 + i * 16 + (lane & 15);
        aoff[i] = ra * 64 + (((lane >> 4) ^ (ra & 3)) * 16);
        int rb = wn * 64 + i * 16 + (lane & 15);
        boff[i] = rb * 64 + (((lane >> 4) ^ (rb & 3)) * 16);
    }
    f32x4 acc[4][4];
#pragma unroll
    for (int i = 0; i < 4; ++i)
#pragma unroll
        for (int j = 0; j < 4; ++j) acc[i][j] = f32x4{0.f, 0.f, 0.f, 0.f};
    float4 pa0 = *(const float4*)(ag + 0), pa1 = *(const float4*)(ag + 4);
    float4 pa2 = *(const float4*)(ag + 8), pa3 = *(const float4*)(ag + 12);
    float4 pb0 = *(const float4*)(bg + 0), pb1 = *(const float4*)(bg + 4);
    float4 pb2 = *(const float4*)(bg + 8), pb3 = *(const float4*)(bg + 12);
    const int NS = HH / 32;
    for (int s = 0; s < NS; ++s) {
        __syncthreads();
        uint4 hi, lo;
        cvt8(pa0, pa1, hi, lo);
        *(uint4*)(smem + AHI1 + au0) = hi; *(uint4*)(smem + ALO1 + au0) = lo;
        cvt8(pa2, pa3, hi, lo);
        *(uint4*)(smem + AHI1 + au1) = hi; *(uint4*)(smem + ALO1 + au1) = lo;
        cvt8(pb0, pb1, hi, lo);
        *(uint4*)(smem + BHI1 + au0) = hi; *(uint4*)(smem + BLO1 + au0) = lo;
        cvt8(pb2, pb3, hi, lo);
        *(uint4*)(smem + BHI1 + au1) = hi; *(uint4*)(smem + BLO1 + au1) = lo;
        __syncthreads();
        if (s + 1 < NS) {
            const int k0 = (s + 1) * 32;
            pa0 = *(const float4*)(ag + k0); pa1 = *(const float4*)(ag + k0 + 4);
            pa2 = *(const float4*)(ag + k0 + 8); pa3 = *(const float4*)(ag + k0 + 12);
            pb0 = *(const float4*)(bg + k0); pb1 = *(const float4*)(bg + k0 + 4);
            pb2 = *(const float4*)(bg + k0 + 8); pb3 = *(const float4*)(bg + k0 + 12);
        }
        bf16v8 ah[4], al[4], bh[4], bl[4];
#pragma unroll
        for (int i = 0; i < 4; ++i) {
            ah[i] = *(const bf16v8*)(smem + AHI1 + aoff[i]);
            al[i] = *(const bf16v8*)(smem + ALO1 + aoff[i]);
            bh[i] = *(const bf16v8*)(smem + BHI1 + boff[i]);
            bl[i] = *(const bf16v8*)(smem + BLO1 + boff[i]);
        }
#pragma unroll
        for (int i = 0; i < 4; ++i)
#pragma unroll
            for (int j = 0; j < 4; ++j) {
                acc[i][j] = __builtin_amdgcn_mfma_f32_16x16x32_bf16(ah[i], bh[j], acc[i][j], 0, 0, 0);
                acc[i][j] = __builtin_amdgcn_mfma_f32_16x16x32_bf16(ah[i], bl[j], acc[i][j], 0, 0, 0);
                acc[i][j] = __builtin_amdgcn_mfma_f32_16x16x32_bf16(al[i], bh[j], acc[i][j], 0, 0, 0);
            }
    }
#pragma unroll
    for (int mi = 0; mi < 4; ++mi)
#pragma unroll
        for (int np = 0; np < 2; ++np) {
            const f32x4 g = acc[mi][np], u = acc[mi][np + 2];
            const int colp = n0 + wn * 32 + np * 16 + (lane & 15);
#pragma unroll
            for (int j = 0; j < 4; ++j) {
                const int r = m0 + wm * 64 + mi * 16 + ((lane >> 4) << 2) + j;
                if (r < cnt) {
                    const float gg = g[j];
                    inter[(size_t)(base + r) * II + colp] = gg / (1.f + expf(-gg)) * u[j];
                }
            }
        }
}

__global__ __launch_bounds__(256, 2) void moe_down_r4(
    const float* __restrict__ inter, const float* __restrict__ Wd,
    const int* __restrict__ counts, const int* __restrict__ offsets,
    const int* __restrict__ bucket_tok, const float* __restrict__ bucket_w,
    float* __restrict__ out)
{
    const int bid = blockIdx.x;
    const int e = bid & 7;
    const int rem = bid >> 3;
    const int mb = rem >> 4, nb = rem & 15;
    const int cnt = counts[e];
    const int m0 = mb * 128;
    if (m0 >= cnt) return;
    const int n0 = nb * 128;
    const int base = offsets[e];
    __shared__ unsigned char smem[32768];
    const int tid = threadIdx.x;
    const int lane = tid & 63;
    const int wid = tid >> 6;
    const int wm = wid >> 1, wn = wid & 1;
    const int srow = tid >> 1;
    const int sseg = tid & 1;
    const int arow = m0 + srow;
    const int asafe = (arow < cnt) ? arow : 0;
    const float* ag = inter + (size_t)(base + asafe) * II + sseg * 16;
    const float* bg = Wd + ((size_t)e * HH + n0 + srow) * II + sseg * 16;
    const int au0 = srow * 64 + (((sseg << 1) | 0) ^ (srow & 3)) * 16;
    const int au1 = srow * 64 + (((sseg << 1) | 1) ^ (srow & 3)) * 16;
    int aoff[4], boff[4];
#pragma unroll
    for (int i = 0; i < 4; ++i) {
        int ra = wm * 64 + i * 16 + (lane & 15);
        aoff[i] = ra * 64 + (((lane >> 4) ^ (ra & 3)) * 16);
        int rb = wn * 64 + i * 16 + (lane & 15);
        boff[i] = rb * 64 + (((lane >> 4) ^ (rb & 3)) * 16);
    }
    f32x4 acc[4][4];
#pragma unroll
    for (int i = 0; i < 4; ++i)
#pragma unroll
        for (int j = 0; j < 4; ++j) acc[i][j] = f32x4{0.f, 0.f, 0.f, 0.f};
    float4 pa0 = *(const float4*)(ag + 0), pa1 = *(const float4*)(ag + 4);
    float4 pa2 = *(const float4*)(ag + 8), pa3 = *(const float4*)(ag + 12);
    float4 pb0 = *(const float4*)(bg + 0), pb1 = *(const float4*)(bg + 4);
    float4 pb2 = *(const float4*)(bg + 8), pb3 = *(const float4*)(bg + 12);
    const int NS = II / 32;
    for (int s = 0; s < NS; ++s) {
        __syncthreads();
        uint4 hi, lo;
        cvt8(pa0, pa1, hi, lo);
        *(uint4*)(smem + AHI1 + au0) = hi; *(uint4*)(smem + ALO1 + au0) = lo;
        cvt8(pa2, pa3, hi, lo);
        *(uint4*)(smem + AHI1 + au1) = hi; *(uint4*)(smem + ALO1 + au1) = lo;
        cvt8(pb0, pb1, hi, lo);
        *(uint4*)(smem + BHI1 + au0) = hi; *(uint4*)(smem + BLO1 + au0) = lo;
        cvt8(pb2, pb3, hi, lo);
        *(uint4*)(smem + BHI1 + au1) = hi; *(uint4*)(smem + BLO1 + au1) = lo;
        __syncthreads();
        if (s + 1 < NS) {
            const int k0 = (s + 1) * 32;
            pa0 = *(const float4*)(ag + k0); pa1 = *(const float4*)(ag + k0 + 4);
            pa2 = *(const float4*)(ag + k0 + 8); pa3 = *(const float4*)(ag + k0 + 12);
            pb0 = *(const float4*)(bg + k0); pb1 = *(const float4*)(bg + k0 + 4);
            pb2 = *(const float4*)(bg + k0 + 8); pb3 = *(const float4*)(bg + k0 + 12);
        }
        bf16v8 ah[4], al[4], bh[4], bl[4];
#pragma unroll
        for (int i = 0; i < 4; ++i) {
            ah[i] = *(const bf16v8*)(smem + AHI1 + aoff[i]);
            al[i] = *(const bf16v8*)(smem + ALO1 + aoff[i]);
            bh[i] = *(const bf16v8*)(smem + BHI1 + boff[i]);
            bl[i] = *(const bf16v8*)(smem + BLO1 + boff[i]);
        }
#pragma unroll
        for (int i = 0; i < 4; ++i)
#pragma unroll
            for (int j = 0; j < 4; ++j) {
                acc[i][j] = __builtin_amdgcn_mfma_f32_16x16x32_bf16(ah[i], bh[j], acc[i][j], 0, 0, 0);
                acc[i][j] = __builtin_amdgcn_mfma_f32_16x16x32_bf16(ah[i], bl[j], acc[i][j], 0, 0, 0);
                acc[i][j] = __builtin_amdgcn_mfma_f32_16x16x32_bf16(al[i], bh[j], acc[i][j], 0, 0, 0);
            }
    }
#pragma unroll
    for (int mi = 0; mi < 4; ++mi) {
        int rtok[4]; float rw[4]; int rok[4];
#pragma unroll
        for (int j = 0; j < 4; ++j) {
            const int r = m0 + wm * 64 + mi * 16 + ((lane >> 4) << 2) + j;
            rok[j] = (r < cnt);
            rtok[j] = rok[j] ? bucket_tok[e * TT + r] : 0;
            rw[j] = rok[j] ? bucket_w[e * TT + r] : 0.f;
        }
#pragma unroll
        for (int ni = 0; ni < 4; ++ni) {
            const int col = n0 + wn * 64 + ni * 16 + (lane & 15);
#pragma unroll
            for (int j = 0; j < 4; ++j)
                if (rok[j])
                    atomicAdd(out + (size_t)rtok[j] * HH + col, rw[j] * acc[mi][ni][j]);
        }
    }
}

// ---------------------------------------------------------------------------
// Launch
// ---------------------------------------------------------------------------
extern "C" void kernel_launch(void* const* d_in, const int* in_sizes, int n_in,
                              void* d_out, int out_size, void* d_ws, size_t ws_size,
                              hipStream_t stream)
{
    const float* x   = (const float*)d_in[0];
    const float* gw  = (const float*)d_in[1];
    const float* wgu = (const float*)d_in[2];
    const float* wd  = (const float*)d_in[3];

    float* out_final  = (float*)d_out;
    float* out_logits = out_final + (size_t)TT * HH;
    float* out_aux    = out_logits + (size_t)TT * EE;

    int*   counts     = (int*)d_ws;
    int*   offsets    = counts + 8;
    int*   bucket_tok = (int*)d_ws + 64;
    float* bucket_w   = (float*)d_ws + 64 + EE * TT;

    // split-array layout (bytes) after the 262400-byte header
    const size_t HDR   = 262400;
    const size_t SZ_X  = (size_t)TT * HH * 2;          // 16.78 MB per component
    const size_t SZ_GU = (size_t)EE * TWOI * HH * 2;   // 50.33 MB
    const size_t SZ_WD = (size_t)EE * HH * II * 2;     // 25.17 MB
    const size_t SZ_I  = (size_t)2 * TT * II * 2;      // 12.58 MB
    const size_t need = HDR + 2 * (SZ_X + SZ_GU + SZ_WD + SZ_I);

    hipMemsetAsync(d_ws, 0, 256, stream);
    hipMemsetAsync(d_out, 0, sizeof(float) * (size_t)TT * HH, stream);

    if (ws_size >= need) {
        unsigned char* p = (unsigned char*)d_ws + HDR;
        unsigned short* xhi  = (unsigned short*)p;            p += SZ_X;
        unsigned short* xlo  = (unsigned short*)p;            p += SZ_X;
        unsigned short* guhi = (unsigned short*)p;            p += SZ_GU;
        unsigned short* gulo = (unsigned short*)p;            p += SZ_GU;
        unsigned short* wdhi = (unsigned short*)p;            p += SZ_WD;
        unsigned short* wdlo = (unsigned short*)p;            p += SZ_WD;
        unsigned short* ihi  = (unsigned short*)p;            p += SZ_I;
        unsigned short* ilo  = (unsigned short*)p;

        cvt_split<<<2048, 256, 0, stream>>>(wgu, guhi, gulo, EE * TWOI * HH / 8);
        cvt_split<<<2048, 256, 0, stream>>>(wd, wdhi, wdlo, EE * HH * II / 8);
        router_kernel<<<TT / 4, 256, 0, stream>>>(x, gw, out_logits, counts,
                                                  bucket_tok, bucket_w, xhi, xlo, 1);
        finalize_router<<<1, 256, 0, stream>>>(out_logits, counts, offsets, out_aux);
        moe_gateup_v2<<<12 * 32 * EE, 256, 0, stream>>>(
            xhi, xlo, guhi, gulo, counts, offsets, bucket_tok, ihi, ilo);
        moe_down_v2<<<16 * 32 * EE, 256, 0, stream>>>(
            ihi, ilo, wdhi, wdlo, counts, offsets, bucket_tok, bucket_w, out_final);
    } else {
        float* inter = (float*)d_ws + 64 + 2 * EE * TT;
        router_kernel<<<TT / 4, 256, 0, stream>>>(x, gw, out_logits, counts,
                                                  bucket_tok, bucket_w,
                                                  (unsigned short*)counts,
                                                  (unsigned short*)counts, 0);
        finalize_router<<<1, 256, 0, stream>>>(out_logits, counts, offsets, out_aux);
        moe_gateup_r4<<<12 * 32 * EE, 256, 0, stream>>>(x, wgu, counts, offsets,
                                                        bucket_tok, inter);
        moe_down_r4<<<16 * 32 * EE, 256, 0, stream>>>(inter, wd, counts, offsets,
                                                      bucket_tok, bucket_w, out_final);
    }
}

// Round 7
// 647.527 us; speedup vs baseline: 2.0815x; 2.0815x over previous
//
#include <hip/hip_runtime.h>
#include <hip/hip_bf16.h>
#include <math.h>

// Problem constants: B=2,S=2048 -> T=4096 tokens, H=2048, E=8, I=768, top-2
#define TT 4096
#define HH 2048
#define EE 8
#define II 768
#define TWOI 1536

typedef __attribute__((ext_vector_type(8))) short bf16v8;   // 8 bf16 = 4 VGPR
typedef __attribute__((ext_vector_type(4))) float f32x4;

// ---------------------------------------------------------------------------
// Fast fp32 -> (hi, lo) bf16 split, 8 elems.
// hi = truncate-to-bf16 (top 16 bits, packed pairwise by v_perm_b32);
// lo = fp32 residual f - hi (exact), truncated to bf16 the same way.
// Combined ~16 mantissa bits; ~3 VALU/elem vs ~10 for the RNE version.
// v_perm_b32 semantics: sel byte k<4 -> byte k of src1(LOW), k in 4..7 ->
// byte k-4 of src0(HIGH). perm(f1, f0, 0x07060302) = [f0.b2,f0.b3,f1.b2,f1.b3]
// = {bf16(f0) in low half, bf16(f1) in high half}.
// ---------------------------------------------------------------------------
static __device__ __forceinline__ void cvt8f(const float4 v0, const float4 v1,
                                             uint4& hi, uint4& lo) {
    unsigned u[8] = {__float_as_uint(v0.x), __float_as_uint(v0.y),
                     __float_as_uint(v0.z), __float_as_uint(v0.w),
                     __float_as_uint(v1.x), __float_as_uint(v1.y),
                     __float_as_uint(v1.z), __float_as_uint(v1.w)};
    unsigned s[8];
#pragma unroll
    for (int i = 0; i < 8; ++i) {
        const float r = __uint_as_float(u[i]) - __uint_as_float(u[i] & 0xFFFF0000u);
        s[i] = __float_as_uint(r);
    }
    hi.x = __builtin_amdgcn_perm(u[1], u[0], 0x07060302);
    hi.y = __builtin_amdgcn_perm(u[3], u[2], 0x07060302);
    hi.z = __builtin_amdgcn_perm(u[5], u[4], 0x07060302);
    hi.w = __builtin_amdgcn_perm(u[7], u[6], 0x07060302);
    lo.x = __builtin_amdgcn_perm(s[1], s[0], 0x07060302);
    lo.y = __builtin_amdgcn_perm(s[3], s[2], 0x07060302);
    lo.z = __builtin_amdgcn_perm(s[5], s[4], 0x07060302);
    lo.w = __builtin_amdgcn_perm(s[7], s[6], 0x07060302);
}

// ---------------------------------------------------------------------------
// Router: one wave per token (R2/R4-verified).
// ---------------------------------------------------------------------------
__global__ __launch_bounds__(256) void router_kernel(
    const float* __restrict__ x, const float* __restrict__ gw,
    float* __restrict__ logits_out, int* __restrict__ counts,
    int* __restrict__ bucket_tok, float* __restrict__ bucket_w)
{
    const int wave = threadIdx.x >> 6;
    const int lane = threadIdx.x & 63;
    const int t = blockIdx.x * 4 + wave;

    float acc[EE];
#pragma unroll
    for (int e = 0; e < EE; ++e) acc[e] = 0.f;

    const float4* xr = (const float4*)(x + (size_t)t * HH);
    for (int i = lane; i < HH / 4; i += 64) {
        const float4 v = xr[i];
        const float* g = gw + (size_t)(i * 4) * EE;
#pragma unroll
        for (int e = 0; e < EE; ++e)
            acc[e] += v.x * g[e] + v.y * g[e + EE]
                    + v.z * g[e + 2 * EE] + v.w * g[e + 3 * EE];
    }
#pragma unroll
    for (int e = 0; e < EE; ++e) {
#pragma unroll
        for (int off = 32; off > 0; off >>= 1)
            acc[e] += __shfl_xor(acc[e], off, 64);
    }

    if (lane == 0) {
        float mx = acc[0];
#pragma unroll
        for (int e = 1; e < EE; ++e) mx = fmaxf(mx, acc[e]);
        float p[EE]; float s = 0.f;
#pragma unroll
        for (int e = 0; e < EE; ++e) { p[e] = expf(acc[e] - mx); s += p[e]; }
        const float inv = 1.f / s;
#pragma unroll
        for (int e = 0; e < EE; ++e) {
            p[e] *= inv;
            logits_out[(size_t)t * EE + e] = acc[e];
        }
        int i0 = 0;
#pragma unroll
        for (int e = 1; e < EE; ++e) if (p[e] > p[i0]) i0 = e;
        int i1 = (i0 == 0) ? 1 : 0;
#pragma unroll
        for (int e = 0; e < EE; ++e) if (e != i0 && p[e] > p[i1]) i1 = e;
        const float denom = 1.f / (p[i0] + p[i1]);
        const float w0 = p[i0] * denom, w1 = p[i1] * denom;
        int pos0 = atomicAdd(&counts[i0], 1);
        bucket_tok[i0 * TT + pos0] = t; bucket_w[i0 * TT + pos0] = w0;
        int pos1 = atomicAdd(&counts[i1], 1);
        bucket_tok[i1 * TT + pos1] = t; bucket_w[i1 * TT + pos1] = w1;
    }
}

__global__ __launch_bounds__(256) void finalize_router(
    const float* __restrict__ logits, const int* __restrict__ counts,
    int* __restrict__ offsets, float* __restrict__ aux_out)
{
    __shared__ float sums[EE];
    if (threadIdx.x < EE) sums[threadIdx.x] = 0.f;
    __syncthreads();
    float loc[EE];
#pragma unroll
    for (int e = 0; e < EE; ++e) loc[e] = 0.f;
    for (int t = threadIdx.x; t < TT; t += 256) {
        const float* lr = logits + (size_t)t * EE;
        float l[EE]; float mx = -1e30f;
#pragma unroll
        for (int e = 0; e < EE; ++e) { l[e] = lr[e]; mx = fmaxf(mx, l[e]); }
        float s = 0.f, p[EE];
#pragma unroll
        for (int e = 0; e < EE; ++e) { p[e] = expf(l[e] - mx); s += p[e]; }
        const float inv = 1.f / s;
#pragma unroll
        for (int e = 0; e < EE; ++e) loc[e] += p[e] * inv;
    }
#pragma unroll
    for (int e = 0; e < EE; ++e) atomicAdd(&sums[e], loc[e]);
    __syncthreads();
    if (threadIdx.x == 0) {
        int o = 0; float aux = 0.f;
        for (int e = 0; e < EE; ++e) {
            offsets[e] = o; o += counts[e];
            aux += (sums[e] / (float)TT) * ((float)counts[e] / (float)TT);
        }
        aux_out[0] = aux * (float)EE * 0.001f;
    }
}

// ===========================================================================
// v3 GEMMs = R4 structure (in-loop split, BK=32 fp32, 128-row tiles, small
// ws footprint) + cheap perm-based split + padded LDS rows (80B, no XOR):
// row stride 80B -> bank = (row*20 + unit*4 + w) mod 32, period-8 over rows
// => exactly 2 lanes/bank on reads AND writes = free (m136).
// LDS: 4 buffers x 128 x 80B = 40 KB.
// ===========================================================================
#define AHI 0
#define ALO 10240
#define BHI 20480
#define BLO 30720
#define LROW 80

// Stage 1: gate_up + SiLU fuse -> fp32 inter.
__global__ __launch_bounds__(256, 2) void moe_gateup_v3(
    const float* __restrict__ x, const float* __restrict__ Wgu,
    const int* __restrict__ counts, const int* __restrict__ offsets,
    const int* __restrict__ bucket_tok, float* __restrict__ inter)
{
    // bijective chunk swizzle: 3072 blocks -> 8 chunks of 384 (one expert/XCD)
    const int bid = blockIdx.x;
    const int e = bid & 7;
    const int rem = bid >> 3;           // 0..383, n fastest
    const int mb = rem / 12, nb = rem % 12;

    const int cnt = counts[e];
    const int m0 = mb * 128;
    if (m0 >= cnt) return;
    const int n0 = nb * 64;             // pair-col base, [0,768)
    const int base = offsets[e];

    __shared__ unsigned char smem[40960];

    const int tid = threadIdx.x;
    const int lane = tid & 63;
    const int wid = tid >> 6;
    const int wm = wid >> 1, wn = wid & 1;

    // staging: thread -> (row, k-half of 16 fp32)
    const int srow = tid >> 1;          // 0..127
    const int sseg = tid & 1;           // k offset 16*sseg
    const int arow = m0 + srow;
    const int atok = (arow < cnt) ? bucket_tok[e * TT + arow] : 0;
    const float* ag = x + (size_t)atok * HH + sseg * 16;
    const int bblk = srow >> 5, bc = srow & 31;
    const int bj = ((bblk & 1) ? II : 0) + n0 + ((bblk >> 1) << 5) + bc;
    const float* bg = Wgu + ((size_t)e * TWOI + bj) * HH + sseg * 16;
    // LDS write offsets: units sseg*2, sseg*2+1 of the padded 80B row
    const int au0 = srow * LROW + (sseg * 2 + 0) * 16;
    const int au1 = srow * LROW + (sseg * 2 + 1) * 16;

    // fragment read offsets (row = frag row, unit = lane>>4 = k-chunk)
    int aoff[4], boff[4];
#pragma unroll
    for (int i = 0; i < 4; ++i) {
        const int ra = wm * 64 + i * 16 + (lane & 15);
        aoff[i] = ra * LROW + (lane >> 4) * 16;
        const int rb = wn * 64 + i * 16 + (lane & 15);
        boff[i] = rb * LROW + (lane >> 4) * 16;
    }

    f32x4 acc[4][4];
#pragma unroll
    for (int i = 0; i < 4; ++i)
#pragma unroll
        for (int j = 0; j < 4; ++j) acc[i][j] = f32x4{0.f, 0.f, 0.f, 0.f};

    float4 pa0 = *(const float4*)(ag + 0), pa1 = *(const float4*)(ag + 4);
    float4 pa2 = *(const float4*)(ag + 8), pa3 = *(const float4*)(ag + 12);
    float4 pb0 = *(const float4*)(bg + 0), pb1 = *(const float4*)(bg + 4);
    float4 pb2 = *(const float4*)(bg + 8), pb3 = *(const float4*)(bg + 12);

    const int NS = HH / 32;             // 64 K-steps
    for (int s = 0; s < NS; ++s) {
        __syncthreads();
        uint4 hi, lo;
        cvt8f(pa0, pa1, hi, lo);
        *(uint4*)(smem + AHI + au0) = hi; *(uint4*)(smem + ALO + au0) = lo;
        cvt8f(pa2, pa3, hi, lo);
        *(uint4*)(smem + AHI + au1) = hi; *(uint4*)(smem + ALO + au1) = lo;
        cvt8f(pb0, pb1, hi, lo);
        *(uint4*)(smem + BHI + au0) = hi; *(uint4*)(smem + BLO + au0) = lo;
        cvt8f(pb2, pb3, hi, lo);
        *(uint4*)(smem + BHI + au1) = hi; *(uint4*)(smem + BLO + au1) = lo;
        __syncthreads();
        if (s + 1 < NS) {               // prefetch next K-slab (hides under MFMA)
            const int k0 = (s + 1) * 32;
            pa0 = *(const float4*)(ag + k0); pa1 = *(const float4*)(ag + k0 + 4);
            pa2 = *(const float4*)(ag + k0 + 8); pa3 = *(const float4*)(ag + k0 + 12);
            pb0 = *(const float4*)(bg + k0); pb1 = *(const float4*)(bg + k0 + 4);
            pb2 = *(const float4*)(bg + k0 + 8); pb3 = *(const float4*)(bg + k0 + 12);
        }
        bf16v8 ah[4], al[4], bh[4], bl[4];
#pragma unroll
        for (int i = 0; i < 4; ++i) {
            ah[i] = *(const bf16v8*)(smem + AHI + aoff[i]);
            al[i] = *(const bf16v8*)(smem + ALO + aoff[i]);
            bh[i] = *(const bf16v8*)(smem + BHI + boff[i]);
            bl[i] = *(const bf16v8*)(smem + BLO + boff[i]);
        }
#pragma unroll
        for (int i = 0; i < 4; ++i)
#pragma unroll
            for (int j = 0; j < 4; ++j) {
                acc[i][j] = __builtin_amdgcn_mfma_f32_16x16x32_bf16(ah[i], bh[j], acc[i][j], 0, 0, 0);
                acc[i][j] = __builtin_amdgcn_mfma_f32_16x16x32_bf16(ah[i], bl[j], acc[i][j], 0, 0, 0);
                acc[i][j] = __builtin_amdgcn_mfma_f32_16x16x32_bf16(al[i], bh[j], acc[i][j], 0, 0, 0);
            }
    }

    // epilogue: SiLU(gate)*up; fragments j=0,1 are gate, j=2,3 the matching up
#pragma unroll
    for (int mi = 0; mi < 4; ++mi)
#pragma unroll
        for (int np = 0; np < 2; ++np) {
            const f32x4 g = acc[mi][np], u = acc[mi][np + 2];
            const int colp = n0 + wn * 32 + np * 16 + (lane & 15);
#pragma unroll
            for (int j = 0; j < 4; ++j) {
                const int r = m0 + wm * 64 + mi * 16 + ((lane >> 4) << 2) + j;
                if (r < cnt) {
                    const float gg = g[j];
                    const float sv = gg / (1.f + expf(-gg));
                    inter[(size_t)(base + r) * II + colp] = sv * u[j];
                }
            }
        }
}

// Stage 2: down proj, weighted atomic scatter (2 commutative adds/elem).
__global__ __launch_bounds__(256, 2) void moe_down_v3(
    const float* __restrict__ inter, const float* __restrict__ Wd,
    const int* __restrict__ counts, const int* __restrict__ offsets,
    const int* __restrict__ bucket_tok, const float* __restrict__ bucket_w,
    float* __restrict__ out)
{
    // 4096 blocks -> 8 chunks of 512 (one expert/XCD), n fastest
    const int bid = blockIdx.x;
    const int e = bid & 7;
    const int rem = bid >> 3;           // 0..511
    const int mb = rem >> 4, nb = rem & 15;

    const int cnt = counts[e];
    const int m0 = mb * 128;
    if (m0 >= cnt) return;
    const int n0 = nb * 128;
    const int base = offsets[e];

    __shared__ unsigned char smem[40960];

    const int tid = threadIdx.x;
    const int lane = tid & 63;
    const int wid = tid >> 6;
    const int wm = wid >> 1, wn = wid & 1;

    const int srow = tid >> 1;
    const int sseg = tid & 1;
    const int arow = m0 + srow;
    const int asafe = (arow < cnt) ? arow : 0;
    const float* ag = inter + (size_t)(base + asafe) * II + sseg * 16;
    const float* bg = Wd + ((size_t)e * HH + n0 + srow) * II + sseg * 16;
    const int au0 = srow * LROW + (sseg * 2 + 0) * 16;
    const int au1 = srow * LROW + (sseg * 2 + 1) * 16;

    int aoff[4], boff[4];
#pragma unroll
    for (int i = 0; i < 4; ++i) {
        const int ra = wm * 64 + i * 16 + (lane & 15);
        aoff[i] = ra * LROW + (lane >> 4) * 16;
        const int rb = wn * 64 + i * 16 + (lane & 15);
        boff[i] = rb * LROW + (lane >> 4) * 16;
    }

    f32x4 acc[4][4];
#pragma unroll
    for (int i = 0; i < 4; ++i)
#pragma unroll
        for (int j = 0; j < 4; ++j) acc[i][j] = f32x4{0.f, 0.f, 0.f, 0.f};

    float4 pa0 = *(const float4*)(ag + 0), pa1 = *(const float4*)(ag + 4);
    float4 pa2 = *(const float4*)(ag + 8), pa3 = *(const float4*)(ag + 12);
    float4 pb0 = *(const float4*)(bg + 0), pb1 = *(const float4*)(bg + 4);
    float4 pb2 = *(const float4*)(bg + 8), pb3 = *(const float4*)(bg + 12);

    const int NS = II / 32;             // 24 K-steps
    for (int s = 0; s < NS; ++s) {
        __syncthreads();
        uint4 hi, lo;
        cvt8f(pa0, pa1, hi, lo);
        *(uint4*)(smem + AHI + au0) = hi; *(uint4*)(smem + ALO + au0) = lo;
        cvt8f(pa2, pa3, hi, lo);
        *(uint4*)(smem + AHI + au1) = hi; *(uint4*)(smem + ALO + au1) = lo;
        cvt8f(pb0, pb1, hi, lo);
        *(uint4*)(smem + BHI + au0) = hi; *(uint4*)(smem + BLO + au0) = lo;
        cvt8f(pb2, pb3, hi, lo);
        *(uint4*)(smem + BHI + au1) = hi; *(uint4*)(smem + BLO + au1) = lo;
        __syncthreads();
        if (s + 1 < NS) {
            const int k0 = (s + 1) * 32;
            pa0 = *(const float4*)(ag + k0); pa1 = *(const float4*)(ag + k0 + 4);
            pa2 = *(const float4*)(ag + k0 + 8); pa3 = *(const float4*)(ag + k0 + 12);
            pb0 = *(const float4*)(bg + k0); pb1 = *(const float4*)(bg + k0 + 4);
            pb2 = *(const float4*)(bg + k0 + 8); pb3 = *(const float4*)(bg + k0 + 12);
        }
        bf16v8 ah[4], al[4], bh[4], bl[4];
#pragma unroll
        for (int i = 0; i < 4; ++i) {
            ah[i] = *(const bf16v8*)(smem + AHI + aoff[i]);
            al[i] = *(const bf16v8*)(smem + ALO + aoff[i]);
            bh[i] = *(const bf16v8*)(smem + BHI + boff[i]);
            bl[i] = *(const bf16v8*)(smem + BLO + boff[i]);
        }
#pragma unroll
        for (int i = 0; i < 4; ++i)
#pragma unroll
            for (int j = 0; j < 4; ++j) {
                acc[i][j] = __builtin_amdgcn_mfma_f32_16x16x32_bf16(ah[i], bh[j], acc[i][j], 0, 0, 0);
                acc[i][j] = __builtin_amdgcn_mfma_f32_16x16x32_bf16(ah[i], bl[j], acc[i][j], 0, 0, 0);
                acc[i][j] = __builtin_amdgcn_mfma_f32_16x16x32_bf16(al[i], bh[j], acc[i][j], 0, 0, 0);
            }
    }

#pragma unroll
    for (int mi = 0; mi < 4; ++mi) {
        int rtok[4]; float rw[4]; int rok[4];
#pragma unroll
        for (int j = 0; j < 4; ++j) {
            const int r = m0 + wm * 64 + mi * 16 + ((lane >> 4) << 2) + j;
            rok[j] = (r < cnt);
            rtok[j] = rok[j] ? bucket_tok[e * TT + r] : 0;
            rw[j] = rok[j] ? bucket_w[e * TT + r] : 0.f;
        }
#pragma unroll
        for (int ni = 0; ni < 4; ++ni) {
            const int col = n0 + wn * 64 + ni * 16 + (lane & 15);
#pragma unroll
            for (int j = 0; j < 4; ++j)
                if (rok[j])
                    atomicAdd(out + (size_t)rtok[j] * HH + col, rw[j] * acc[mi][ni][j]);
        }
    }
}

// ---------------------------------------------------------------------------
// Launch — small ws footprint (~25 MB): header + buckets + fp32 inter.
// (R6 lesson: the harness re-poisons ALL of d_ws each timed iteration, so
// every extra ws byte costs HBM bandwidth. Keep it minimal.)
// ---------------------------------------------------------------------------
extern "C" void kernel_launch(void* const* d_in, const int* in_sizes, int n_in,
                              void* d_out, int out_size, void* d_ws, size_t ws_size,
                              hipStream_t stream)
{
    const float* x   = (const float*)d_in[0];
    const float* gw  = (const float*)d_in[1];
    const float* wgu = (const float*)d_in[2];
    const float* wd  = (const float*)d_in[3];

    float* out_final  = (float*)d_out;
    float* out_logits = out_final + (size_t)TT * HH;
    float* out_aux    = out_logits + (size_t)TT * EE;

    int*   counts     = (int*)d_ws;
    int*   offsets    = counts + 8;
    int*   bucket_tok = (int*)d_ws + 64;
    float* bucket_w   = (float*)d_ws + 64 + EE * TT;
    float* inter      = (float*)d_ws + 64 + 2 * EE * TT;

    hipMemsetAsync(d_ws, 0, 256, stream);
    hipMemsetAsync(d_out, 0, sizeof(float) * (size_t)TT * HH, stream);

    router_kernel<<<TT / 4, 256, 0, stream>>>(x, gw, out_logits, counts,
                                              bucket_tok, bucket_w);
    finalize_router<<<1, 256, 0, stream>>>(out_logits, counts, offsets, out_aux);
    moe_gateup_v3<<<12 * 32 * EE, 256, 0, stream>>>(x, wgu, counts, offsets,
                                                    bucket_tok, inter);
    moe_down_v3<<<16 * 32 * EE, 256, 0, stream>>>(inter, wd, counts, offsets,
                                                  bucket_tok, bucket_w, out_final);
}

// Round 9
// 632.375 us; speedup vs baseline: 2.1314x; 1.0240x over previous
//
#include <hip/hip_runtime.h>
#include <hip/hip_bf16.h>
#include <math.h>

// Problem constants: B=2,S=2048 -> T=4096 tokens, H=2048, E=8, I=768, top-2
#define TT 4096
#define HH 2048
#define EE 8
#define II 768
#define TWOI 1536

typedef __attribute__((ext_vector_type(8))) short bf16v8;   // 8 bf16 = 4 VGPR
typedef __attribute__((ext_vector_type(4))) float f32x4;

// ---------------------------------------------------------------------------
// Fast fp32 -> (hi, lo) bf16 split, 8 elems (R7-verified).
// hi = truncate-to-bf16; lo = bf16(f - hi) (residual exact in fp32).
// ---------------------------------------------------------------------------
static __device__ __forceinline__ void cvt8f(const float4 v0, const float4 v1,
                                             uint4& hi, uint4& lo) {
    unsigned u[8] = {__float_as_uint(v0.x), __float_as_uint(v0.y),
                     __float_as_uint(v0.z), __float_as_uint(v0.w),
                     __float_as_uint(v1.x), __float_as_uint(v1.y),
                     __float_as_uint(v1.z), __float_as_uint(v1.w)};
    unsigned s[8];
#pragma unroll
    for (int i = 0; i < 8; ++i) {
        const float r = __uint_as_float(u[i]) - __uint_as_float(u[i] & 0xFFFF0000u);
        s[i] = __float_as_uint(r);
    }
    hi.x = __builtin_amdgcn_perm(u[1], u[0], 0x07060302);
    hi.y = __builtin_amdgcn_perm(u[3], u[2], 0x07060302);
    hi.z = __builtin_amdgcn_perm(u[5], u[4], 0x07060302);
    hi.w = __builtin_amdgcn_perm(u[7], u[6], 0x07060302);
    lo.x = __builtin_amdgcn_perm(s[1], s[0], 0x07060302);
    lo.y = __builtin_amdgcn_perm(s[3], s[2], 0x07060302);
    lo.z = __builtin_amdgcn_perm(s[5], s[4], 0x07060302);
    lo.w = __builtin_amdgcn_perm(s[7], s[6], 0x07060302);
}

// ---------------------------------------------------------------------------
// Router: one wave per token (R2/R4/R7-verified).
// ---------------------------------------------------------------------------
__global__ __launch_bounds__(256) void router_kernel(
    const float* __restrict__ x, const float* __restrict__ gw,
    float* __restrict__ logits_out, int* __restrict__ counts,
    int* __restrict__ bucket_tok, float* __restrict__ bucket_w)
{
    const int wave = threadIdx.x >> 6;
    const int lane = threadIdx.x & 63;
    const int t = blockIdx.x * 4 + wave;

    float acc[EE];
#pragma unroll
    for (int e = 0; e < EE; ++e) acc[e] = 0.f;

    const float4* xr = (const float4*)(x + (size_t)t * HH);
    for (int i = lane; i < HH / 4; i += 64) {
        const float4 v = xr[i];
        const float* g = gw + (size_t)(i * 4) * EE;
#pragma unroll
        for (int e = 0; e < EE; ++e)
            acc[e] += v.x * g[e] + v.y * g[e + EE]
                    + v.z * g[e + 2 * EE] + v.w * g[e + 3 * EE];
    }
#pragma unroll
    for (int e = 0; e < EE; ++e) {
#pragma unroll
        for (int off = 32; off > 0; off >>= 1)
            acc[e] += __shfl_xor(acc[e], off, 64);
    }

    if (lane == 0) {
        float mx = acc[0];
#pragma unroll
        for (int e = 1; e < EE; ++e) mx = fmaxf(mx, acc[e]);
        float p[EE]; float s = 0.f;
#pragma unroll
        for (int e = 0; e < EE; ++e) { p[e] = expf(acc[e] - mx); s += p[e]; }
        const float inv = 1.f / s;
#pragma unroll
        for (int e = 0; e < EE; ++e) {
            p[e] *= inv;
            logits_out[(size_t)t * EE + e] = acc[e];
        }
        int i0 = 0;
#pragma unroll
        for (int e = 1; e < EE; ++e) if (p[e] > p[i0]) i0 = e;
        int i1 = (i0 == 0) ? 1 : 0;
#pragma unroll
        for (int e = 0; e < EE; ++e) if (e != i0 && p[e] > p[i1]) i1 = e;
        const float denom = 1.f / (p[i0] + p[i1]);
        const float w0 = p[i0] * denom, w1 = p[i1] * denom;
        int pos0 = atomicAdd(&counts[i0], 1);
        bucket_tok[i0 * TT + pos0] = t; bucket_w[i0 * TT + pos0] = w0;
        int pos1 = atomicAdd(&counts[i1], 1);
        bucket_tok[i1 * TT + pos1] = t; bucket_w[i1 * TT + pos1] = w1;
    }
}

__global__ __launch_bounds__(256) void finalize_router(
    const float* __restrict__ logits, const int* __restrict__ counts,
    int* __restrict__ offsets, float* __restrict__ aux_out)
{
    __shared__ float sums[EE];
    if (threadIdx.x < EE) sums[threadIdx.x] = 0.f;
    __syncthreads();
    float loc[EE];
#pragma unroll
    for (int e = 0; e < EE; ++e) loc[e] = 0.f;
    for (int t = threadIdx.x; t < TT; t += 256) {
        const float* lr = logits + (size_t)t * EE;
        float l[EE]; float mx = -1e30f;
#pragma unroll
        for (int e = 0; e < EE; ++e) { l[e] = lr[e]; mx = fmaxf(mx, l[e]); }
        float s = 0.f, p[EE];
#pragma unroll
        for (int e = 0; e < EE; ++e) { p[e] = expf(l[e] - mx); s += p[e]; }
        const float inv = 1.f / s;
#pragma unroll
        for (int e = 0; e < EE; ++e) loc[e] += p[e] * inv;
    }
#pragma unroll
    for (int e = 0; e < EE; ++e) atomicAdd(&sums[e], loc[e]);
    __syncthreads();
    if (threadIdx.x == 0) {
        int o = 0; float aux = 0.f;
        for (int e = 0; e < EE; ++e) {
            offsets[e] = o; o += counts[e];
            aux += (sums[e] / (float)TT) * ((float)counts[e] / (float)TT);
        }
        aux_out[0] = aux * (float)EE * 0.001f;
    }
}

// ===========================================================================
// v4 GEMMs: block 128 rows x 256 phys cols, BK=32, 4 waves each computing
// 128x64 (8x4 fragments, 96 MFMA per K-step per wave vs 24 LDS reads —
// 0.25 reads/MFMA; v3's 64x64 was 0.33 -> LDS-BW-bound at MfmaUtil 33%).
// 80B-padded LDS rows (2-lane/bank min on reads+writes). LDS 60 KB.
// ===========================================================================
#define AHI 0
#define ALO 10240
#define BHI 20480
#define BLO 40960
#define LROW 80

// Stage 1: gate_up + SiLU fuse -> fp32 inter.
// B LDS rows r in [0,256): w=r>>6, sub=r&63, half=sub>>5 (0 gate,1 up),
// c=sub&31 -> weight col = half*II + nb*128 + w*32 + c.
__global__ __launch_bounds__(256, 2) void moe_gateup_v4(
    const float* __restrict__ x, const float* __restrict__ Wgu,
    const int* __restrict__ counts, const int* __restrict__ offsets,
    const int* __restrict__ bucket_tok, float* __restrict__ inter)
{
    // 1536 blocks: expert = bid&7 (XCD-pinned), rem = 0..191: mb=rem/6, nb=rem%6
    const int bid = blockIdx.x;
    const int e = bid & 7;
    const int rem = bid >> 3;
    const int mb = rem / 6, nb = rem % 6;

    const int cnt = counts[e];
    const int m0 = mb * 128;
    if (m0 >= cnt) return;
    const int n0 = nb * 128;            // pair-col base, [0,768)
    const int base = offsets[e];

    __shared__ unsigned char smem[61440];

    const int tid = threadIdx.x;
    const int lane = tid & 63;
    const int w = tid >> 6;             // wave id = column quarter

    // staging: thread -> (row srow, k-half sseg); A row + 2 B rows
    const int srow = tid >> 1;          // 0..127
    const int sseg = tid & 1;           // k offset 16*sseg
    const int arow = m0 + srow;
    const int atok = (arow < cnt) ? bucket_tok[e * TT + arow] : 0;
    const float* ag = x + (size_t)atok * HH + sseg * 16;

    // B rows srow and srow+128
    int bcol[2];
#pragma unroll
    for (int h = 0; h < 2; ++h) {
        const int r = srow + h * 128;
        const int wq = r >> 6, sub = r & 63;
        bcol[h] = ((sub >> 5) ? II : 0) + n0 + wq * 32 + (sub & 31);
    }
    const float* bg0 = Wgu + ((size_t)e * TWOI + bcol[0]) * HH + sseg * 16;
    const float* bg1 = Wgu + ((size_t)e * TWOI + bcol[1]) * HH + sseg * 16;

    // LDS write offsets (units sseg*2, sseg*2+1 of padded 80B rows)
    const int au0 = srow * LROW + (sseg * 2 + 0) * 16;
    const int au1 = srow * LROW + (sseg * 2 + 1) * 16;
    const int bu0 = srow * LROW + (sseg * 2 + 0) * 16;
    const int bu1 = srow * LROW + (sseg * 2 + 1) * 16;
    const int bv0 = (srow + 128) * LROW + (sseg * 2 + 0) * 16;
    const int bv1 = (srow + 128) * LROW + (sseg * 2 + 1) * 16;

    // fragment read offsets: A rows mi*16+(lane&15), B rows w*64+j*16+(lane&15)
    int aoff[8], boff[4];
#pragma unroll
    for (int i = 0; i < 8; ++i) {
        const int ra = i * 16 + (lane & 15);
        aoff[i] = ra * LROW + (lane >> 4) * 16;
    }
#pragma unroll
    for (int j = 0; j < 4; ++j) {
        const int rb = w * 64 + j * 16 + (lane & 15);
        boff[j] = rb * LROW + (lane >> 4) * 16;
    }

    f32x4 acc[8][4];
#pragma unroll
    for (int i = 0; i < 8; ++i)
#pragma unroll
        for (int j = 0; j < 4; ++j) acc[i][j] = f32x4{0.f, 0.f, 0.f, 0.f};

    float4 pa0 = *(const float4*)(ag + 0), pa1 = *(const float4*)(ag + 4);
    float4 pa2 = *(const float4*)(ag + 8), pa3 = *(const float4*)(ag + 12);
    float4 pb0 = *(const float4*)(bg0 + 0), pb1 = *(const float4*)(bg0 + 4);
    float4 pb2 = *(const float4*)(bg0 + 8), pb3 = *(const float4*)(bg0 + 12);
    float4 pc0 = *(const float4*)(bg1 + 0), pc1 = *(const float4*)(bg1 + 4);
    float4 pc2 = *(const float4*)(bg1 + 8), pc3 = *(const float4*)(bg1 + 12);

    const int NS = HH / 32;             // 64 K-steps
    for (int s = 0; s < NS; ++s) {
        __syncthreads();
        uint4 hi, lo;
        cvt8f(pa0, pa1, hi, lo);
        *(uint4*)(smem + AHI + au0) = hi; *(uint4*)(smem + ALO + au0) = lo;
        cvt8f(pa2, pa3, hi, lo);
        *(uint4*)(smem + AHI + au1) = hi; *(uint4*)(smem + ALO + au1) = lo;
        cvt8f(pb0, pb1, hi, lo);
        *(uint4*)(smem + BHI + bu0) = hi; *(uint4*)(smem + BLO + bu0) = lo;
        cvt8f(pb2, pb3, hi, lo);
        *(uint4*)(smem + BHI + bu1) = hi; *(uint4*)(smem + BLO + bu1) = lo;
        cvt8f(pc0, pc1, hi, lo);
        *(uint4*)(smem + BHI + bv0) = hi; *(uint4*)(smem + BLO + bv0) = lo;
        cvt8f(pc2, pc3, hi, lo);
        *(uint4*)(smem + BHI + bv1) = hi; *(uint4*)(smem + BLO + bv1) = lo;
        __syncthreads();
        if (s + 1 < NS) {               // prefetch next K-slab (hides under MFMA)
            const int k0 = (s + 1) * 32;
            pa0 = *(const float4*)(ag + k0); pa1 = *(const float4*)(ag + k0 + 4);
            pa2 = *(const float4*)(ag + k0 + 8); pa3 = *(const float4*)(ag + k0 + 12);
            pb0 = *(const float4*)(bg0 + k0); pb1 = *(const float4*)(bg0 + k0 + 4);
            pb2 = *(const float4*)(bg0 + k0 + 8); pb3 = *(const float4*)(bg0 + k0 + 12);
            pc0 = *(const float4*)(bg1 + k0); pc1 = *(const float4*)(bg1 + k0 + 4);
            pc2 = *(const float4*)(bg1 + k0 + 8); pc3 = *(const float4*)(bg1 + k0 + 12);
        }
        bf16v8 bh[4], bl[4];
#pragma unroll
        for (int j = 0; j < 4; ++j) {
            bh[j] = *(const bf16v8*)(smem + BHI + boff[j]);
            bl[j] = *(const bf16v8*)(smem + BLO + boff[j]);
        }
#pragma unroll
        for (int i = 0; i < 8; ++i) {
            const bf16v8 ah = *(const bf16v8*)(smem + AHI + aoff[i]);
            const bf16v8 al = *(const bf16v8*)(smem + ALO + aoff[i]);
#pragma unroll
            for (int j = 0; j < 4; ++j) {
                acc[i][j] = __builtin_amdgcn_mfma_f32_16x16x32_bf16(ah, bh[j], acc[i][j], 0, 0, 0);
                acc[i][j] = __builtin_amdgcn_mfma_f32_16x16x32_bf16(ah, bl[j], acc[i][j], 0, 0, 0);
                acc[i][j] = __builtin_amdgcn_mfma_f32_16x16x32_bf16(al, bh[j], acc[i][j], 0, 0, 0);
            }
        }
    }

    // epilogue: SiLU(gate)*up; frags j=0,1 gate, j=2,3 matching up
#pragma unroll
    for (int mi = 0; mi < 8; ++mi)
#pragma unroll
        for (int np = 0; np < 2; ++np) {
            const f32x4 g = acc[mi][np], u = acc[mi][np + 2];
            const int colp = n0 + w * 32 + np * 16 + (lane & 15);
#pragma unroll
            for (int j = 0; j < 4; ++j) {
                const int r = m0 + mi * 16 + ((lane >> 4) << 2) + j;
                if (r < cnt) {
                    const float gg = g[j];
                    const float sv = gg / (1.f + expf(-gg));
                    inter[(size_t)(base + r) * II + colp] = sv * u[j];
                }
            }
        }
}

// Stage 2: down proj, weighted atomic scatter. Block 128 rows x 256 h-cols.
__global__ __launch_bounds__(256, 2) void moe_down_v4(
    const float* __restrict__ inter, const float* __restrict__ Wd,
    const int* __restrict__ counts, const int* __restrict__ offsets,
    const int* __restrict__ bucket_tok, const float* __restrict__ bucket_w,
    float* __restrict__ out)
{
    // 2048 blocks: e = bid&7, rem 0..255: mb=rem>>3, nb=rem&7
    const int bid = blockIdx.x;
    const int e = bid & 7;
    const int rem = bid >> 3;
    const int mb = rem >> 3, nb = rem & 7;

    const int cnt = counts[e];
    const int m0 = mb * 128;
    if (m0 >= cnt) return;
    const int n0 = nb * 256;
    const int base = offsets[e];

    __shared__ unsigned char smem[61440];

    const int tid = threadIdx.x;
    const int lane = tid & 63;
    const int w = tid >> 6;

    const int srow = tid >> 1;
    const int sseg = tid & 1;
    const int arow = m0 + srow;
    const int asafe = (arow < cnt) ? arow : 0;
    const float* ag = inter + (size_t)(base + asafe) * II + sseg * 16;
    const float* bg0 = Wd + ((size_t)e * HH + n0 + srow) * II + sseg * 16;
    const float* bg1 = Wd + ((size_t)e * HH + n0 + srow + 128) * II + sseg * 16;

    const int au0 = srow * LROW + (sseg * 2 + 0) * 16;
    const int au1 = srow * LROW + (sseg * 2 + 1) * 16;
    const int bu0 = au0, bu1 = au1;
    const int bv0 = (srow + 128) * LROW + (sseg * 2 + 0) * 16;
    const int bv1 = (srow + 128) * LROW + (sseg * 2 + 1) * 16;

    int aoff[8], boff[4];
#pragma unroll
    for (int i = 0; i < 8; ++i) {
        const int ra = i * 16 + (lane & 15);
        aoff[i] = ra * LROW + (lane >> 4) * 16;
    }
#pragma unroll
    for (int j = 0; j < 4; ++j) {
        const int rb = w * 64 + j * 16 + (lane & 15);
        boff[j] = rb * LROW + (lane >> 4) * 16;
    }

    f32x4 acc[8][4];
#pragma unroll
    for (int i = 0; i < 8; ++i)
#pragma unroll
        for (int j = 0; j < 4; ++j) acc[i][j] = f32x4{0.f, 0.f, 0.f, 0.f};

    float4 pa0 = *(const float4*)(ag + 0), pa1 = *(const float4*)(ag + 4);
    float4 pa2 = *(const float4*)(ag + 8), pa3 = *(const float4*)(ag + 12);
    float4 pb0 = *(const float4*)(bg0 + 0), pb1 = *(const float4*)(bg0 + 4);
    float4 pb2 = *(const float4*)(bg0 + 8), pb3 = *(const float4*)(bg0 + 12);
    float4 pc0 = *(const float4*)(bg1 + 0), pc1 = *(const float4*)(bg1 + 4);
    float4 pc2 = *(const float4*)(bg1 + 8), pc3 = *(const float4*)(bg1 + 12);

    const int NS = II / 32;             // 24 K-steps
    for (int s = 0; s < NS; ++s) {
        __syncthreads();
        uint4 hi, lo;
        cvt8f(pa0, pa1, hi, lo);
        *(uint4*)(smem + AHI + au0) = hi; *(uint4*)(smem + ALO + au0) = lo;
        cvt8f(pa2, pa3, hi, lo);
        *(uint4*)(smem + AHI + au1) = hi; *(uint4*)(smem + ALO + au1) = lo;
        cvt8f(pb0, pb1, hi, lo);
        *(uint4*)(smem + BHI + bu0) = hi; *(uint4*)(smem + BLO + bu0) = lo;
        cvt8f(pb2, pb3, hi, lo);
        *(uint4*)(smem + BHI + bu1) = hi; *(uint4*)(smem + BLO + bu1) = lo;
        cvt8f(pc0, pc1, hi, lo);
        *(uint4*)(smem + BHI + bv0) = hi; *(uint4*)(smem + BLO + bv0) = lo;
        cvt8f(pc2, pc3, hi, lo);
        *(uint4*)(smem + BHI + bv1) = hi; *(uint4*)(smem + BLO + bv1) = lo;
        __syncthreads();
        if (s + 1 < NS) {
            const int k0 = (s + 1) * 32;
            pa0 = *(const float4*)(ag + k0); pa1 = *(const float4*)(ag + k0 + 4);
            pa2 = *(const float4*)(ag + k0 + 8); pa3 = *(const float4*)(ag + k0 + 12);
            pb0 = *(const float4*)(bg0 + k0); pb1 = *(const float4*)(bg0 + k0 + 4);
            pb2 = *(const float4*)(bg0 + k0 + 8); pb3 = *(const float4*)(bg0 + k0 + 12);
            pc0 = *(const float4*)(bg1 + k0); pc1 = *(const float4*)(bg1 + k0 + 4);
            pc2 = *(const float4*)(bg1 + k0 + 8); pc3 = *(const float4*)(bg1 + k0 + 12);
        }
        bf16v8 bh[4], bl[4];
#pragma unroll
        for (int j = 0; j < 4; ++j) {
            bh[j] = *(const bf16v8*)(smem + BHI + boff[j]);
            bl[j] = *(const bf16v8*)(smem + BLO + boff[j]);
        }
#pragma unroll
        for (int i = 0; i < 8; ++i) {
            const bf16v8 ah = *(const bf16v8*)(smem + AHI + aoff[i]);
            const bf16v8 al = *(const bf16v8*)(smem + ALO + aoff[i]);
#pragma unroll
            for (int j = 0; j < 4; ++j) {
                acc[i][j] = __builtin_amdgcn_mfma_f32_16x16x32_bf16(ah, bh[j], acc[i][j], 0, 0, 0);
                acc[i][j] = __builtin_amdgcn_mfma_f32_16x16x32_bf16(ah, bl[j], acc[i][j], 0, 0, 0);
                acc[i][j] = __builtin_amdgcn_mfma_f32_16x16x32_bf16(al, bh[j], acc[i][j], 0, 0, 0);
            }
        }
    }

#pragma unroll
    for (int mi = 0; mi < 8; ++mi) {
        int rtok[4]; float rw[4]; int rok[4];
#pragma unroll
        for (int j = 0; j < 4; ++j) {
            const int r = m0 + mi * 16 + ((lane >> 4) << 2) + j;
            rok[j] = (r < cnt);
            rtok[j] = rok[j] ? bucket_tok[e * TT + r] : 0;
            rw[j] = rok[j] ? bucket_w[e * TT + r] : 0.f;
        }
#pragma unroll
        for (int ni = 0; ni < 4; ++ni) {
            const int col = n0 + w * 64 + ni * 16 + (lane & 15);
#pragma unroll
            for (int j = 0; j < 4; ++j)
                if (rok[j])
                    atomicAdd(out + (size_t)rtok[j] * HH + col, rw[j] * acc[mi][ni][j]);
        }
    }
}

// ---------------------------------------------------------------------------
// Launch — small ws footprint (~25 MB; harness re-poisons all of d_ws each
// timed iteration, so ws bytes cost HBM bandwidth — R6 lesson).
// ---------------------------------------------------------------------------
extern "C" void kernel_launch(void* const* d_in, const int* in_sizes, int n_in,
                              void* d_out, int out_size, void* d_ws, size_t ws_size,
                              hipStream_t stream)
{
    const float* x   = (const float*)d_in[0];
    const float* gw  = (const float*)d_in[1];
    const float* wgu = (const float*)d_in[2];
    const float* wd  = (const float*)d_in[3];

    float* out_final  = (float*)d_out;
    float* out_logits = out_final + (size_t)TT * HH;
    float* out_aux    = out_logits + (size_t)TT * EE;

    int*   counts     = (int*)d_ws;
    int*   offsets    = counts + 8;
    int*   bucket_tok = (int*)d_ws + 64;
    float* bucket_w   = (float*)d_ws + 64 + EE * TT;
    float* inter      = (float*)d_ws + 64 + 2 * EE * TT;

    hipMemsetAsync(d_ws, 0, 256, stream);
    hipMemsetAsync(d_out, 0, sizeof(float) * (size_t)TT * HH, stream);

    router_kernel<<<TT / 4, 256, 0, stream>>>(x, gw, out_logits, counts,
                                              bucket_tok, bucket_w);
    finalize_router<<<1, 256, 0, stream>>>(out_logits, counts, offsets, out_aux);
    moe_gateup_v4<<<6 * 32 * EE, 256, 0, stream>>>(x, wgu, counts, offsets,
                                                   bucket_tok, inter);
    moe_down_v4<<<8 * 32 * EE, 256, 0, stream>>>(inter, wd, counts, offsets,
                                                 bucket_tok, bucket_w, out_final);
}